// Round 1
// baseline (1427.579 us; speedup 1.0000x reference)
//
#include <hip/hip_runtime.h>
#include <hip/hip_bf16.h>

// SimpleSAGE on MI355X.
// Pipeline (uses linearity: spmm(x) @ W == spmm(x @ W)):
//   xw  = x @ w1                    [N,128]  (gemm, K=256)
//   h1  = relu(spmm(xw) + b1)       [N,128]  (csr spmm, fused epilogue)
//   h1w = h1 @ w2                   [N,128]  (gemm, K=128)
//   z   = relu(spmm(h1w) + b2)@wo+bo  [N]    (csr spmm, fused epilogue+reduce)
// CSR built on-device every call (histogram -> scan -> scatter).

#define HID 128

// ---------------- CSR build ----------------
__global__ void hist_kernel(const int* __restrict__ rows, int* __restrict__ deg, int E) {
    int e = blockIdx.x * blockDim.x + threadIdx.x;
    if (e < E) atomicAdd(&deg[rows[e]], 1);
}

__global__ __launch_bounds__(1024) void scan_kernel(const int* __restrict__ deg,
                                                    int* __restrict__ row_ptr,
                                                    int* __restrict__ cursor, int n) {
    __shared__ int s[1024];
    int t = threadIdx.x;
    const int CH = (n + 1023) / 1024;
    int lo = t * CH;
    int hi = lo + CH; if (hi > n) hi = n;
    int sum = 0;
    for (int i = lo; i < hi; ++i) sum += deg[i];
    s[t] = sum;
    __syncthreads();
    // Hillis-Steele inclusive scan
    for (int off = 1; off < 1024; off <<= 1) {
        int v = (t >= off) ? s[t - off] : 0;
        __syncthreads();
        s[t] += v;
        __syncthreads();
    }
    int offset = s[t] - sum;  // exclusive prefix
    for (int i = lo; i < hi; ++i) {
        row_ptr[i] = offset;
        cursor[i] = offset;
        offset += deg[i];
    }
    if (t == 1023) row_ptr[n] = s[1023];
}

__global__ void scatter_kernel(const int* __restrict__ rows, const int* __restrict__ cols,
                               const float* __restrict__ vals, int* __restrict__ cursor,
                               int* __restrict__ scol, float* __restrict__ sval, int E) {
    int e = blockIdx.x * blockDim.x + threadIdx.x;
    if (e < E) {
        int r = rows[e];
        int p = atomicAdd(&cursor[r], 1);
        scol[p] = cols[e];
        sval[p] = vals[e];
    }
}

// ---------------- dense GEMM: C[N,128] = A[N,K] @ W[K,128] ----------------
// block 256 threads, tile 32 rows x 128 cols, thread computes 4x4.
template <int K>
__global__ __launch_bounds__(256) void gemm_nk128(const float* __restrict__ A,
                                                  const float* __restrict__ W,
                                                  float* __restrict__ C, int nrows) {
    __shared__ float a_s[32][32];
    __shared__ float w_s[32][128];
    const int t = threadIdx.x;
    const int tx = t & 31;   // col group (4 cols each)
    const int ty = t >> 5;   // row group (4 rows each)
    const int row0 = blockIdx.x * 32;
    const int col = tx * 4;
    float acc[4][4] = {};

    for (int k0 = 0; k0 < K; k0 += 32) {
        // stage A tile [32][32]
        {
            int r = t >> 3;
            int kk = (t & 7) * 4;
            int gr = row0 + r;
            if (gr >= nrows) gr = nrows - 1;  // clamp (harmless duplicate read)
            const float4 av = *reinterpret_cast<const float4*>(&A[(size_t)gr * K + k0 + kk]);
            *reinterpret_cast<float4*>(&a_s[r][kk]) = av;
        }
        // stage W tile [32][128]
        #pragma unroll
        for (int i = 0; i < 4; ++i) {
            int idx4 = t + i * 256;
            int kk = idx4 >> 5;
            int cc = (idx4 & 31) * 4;
            const float4 wv = *reinterpret_cast<const float4*>(&W[(size_t)(k0 + kk) * 128 + cc]);
            *reinterpret_cast<float4*>(&w_s[kk][cc]) = wv;
        }
        __syncthreads();
        #pragma unroll
        for (int kk = 0; kk < 32; kk += 4) {
            float4 a4[4];
            #pragma unroll
            for (int i = 0; i < 4; ++i)
                a4[i] = *reinterpret_cast<const float4*>(&a_s[ty * 4 + i][kk]);
            #pragma unroll
            for (int q = 0; q < 4; ++q) {
                float4 w4 = *reinterpret_cast<const float4*>(&w_s[kk + q][col]);
                #pragma unroll
                for (int i = 0; i < 4; ++i) {
                    float a = (&a4[i].x)[q];
                    acc[i][0] += a * w4.x;
                    acc[i][1] += a * w4.y;
                    acc[i][2] += a * w4.z;
                    acc[i][3] += a * w4.w;
                }
            }
        }
        __syncthreads();
    }
    #pragma unroll
    for (int i = 0; i < 4; ++i) {
        int r = row0 + ty * 4 + i;
        if (r < nrows) {
            float4 v = make_float4(acc[i][0], acc[i][1], acc[i][2], acc[i][3]);
            *reinterpret_cast<float4*>(&C[(size_t)r * HID + col]) = v;
        }
    }
}

// ---------------- CSR SpMM, one wave per row, lane owns 2 features ----------------
// OUT = relu(spmm(X) + bias)  (FINAL=false, writes [N,128])
// z   = relu(spmm(X) + bias) . wo + bo  (FINAL=true, writes [N])
template <bool FINAL>
__global__ __launch_bounds__(256) void spmm_kernel(const int* __restrict__ row_ptr,
                                                   const int* __restrict__ scol,
                                                   const float* __restrict__ sval,
                                                   const float* __restrict__ X,
                                                   const float* __restrict__ bias,
                                                   const float* __restrict__ wo,
                                                   const float* __restrict__ bo,
                                                   float* __restrict__ out, int nrows) {
    const int wave = threadIdx.x >> 6;
    const int lane = threadIdx.x & 63;
    const int row = blockIdx.x * 4 + wave;
    if (row >= nrows) return;
    const int e0 = row_ptr[row];
    const int e1 = row_ptr[row + 1];
    float ax = 0.f, ay = 0.f;
    for (int e = e0; e < e1; ++e) {
        const int c = scol[e];
        const float v = sval[e];
        const float2 xv = *reinterpret_cast<const float2*>(&X[(size_t)c * HID + lane * 2]);
        ax += v * xv.x;
        ay += v * xv.y;
    }
    const float hx = fmaxf(ax + bias[lane * 2], 0.f);
    const float hy = fmaxf(ay + bias[lane * 2 + 1], 0.f);
    if (!FINAL) {
        *reinterpret_cast<float2*>(&out[(size_t)row * HID + lane * 2]) = make_float2(hx, hy);
    } else {
        float p = hx * wo[lane * 2] + hy * wo[lane * 2 + 1];
        #pragma unroll
        for (int off = 32; off > 0; off >>= 1) p += __shfl_down(p, off, 64);
        if (lane == 0) out[row] = p + bo[0];
    }
}

extern "C" void kernel_launch(void* const* d_in, const int* in_sizes, int n_in,
                              void* d_out, int out_size, void* d_ws, size_t ws_size,
                              hipStream_t stream) {
    const float* x        = (const float*)d_in[0];
    const int*   e_rows   = (const int*)d_in[1];
    const int*   e_cols   = (const int*)d_in[2];
    const float* e_vals   = (const float*)d_in[3];
    const float* w1       = (const float*)d_in[4];
    const float* b1       = (const float*)d_in[5];
    const float* w2       = (const float*)d_in[6];
    const float* b2       = (const float*)d_in[7];
    const float* wo       = (const float*)d_in[8];
    const float* bo       = (const float*)d_in[9];
    float* z = (float*)d_out;

    const int IN_DIM = 256;
    const int N = in_sizes[0] / IN_DIM;
    const int E = in_sizes[1];

    // workspace carve-up
    size_t off = 0;
    auto alloc = [&](size_t bytes) {
        void* p = (char*)d_ws + off;
        off += (bytes + 255) & ~(size_t)255;
        return p;
    };
    float* bufA   = (float*)alloc((size_t)N * HID * 4);  // xw, later h1w
    float* bufB   = (float*)alloc((size_t)N * HID * 4);  // h1
    int*   deg    = (int*)alloc((size_t)N * 4);
    int*   rowptr = (int*)alloc((size_t)(N + 1) * 4);
    int*   cursor = (int*)alloc((size_t)N * 4);
    int*   scol   = (int*)alloc((size_t)E * 4);
    float* sval   = (float*)alloc((size_t)E * 4);
    (void)ws_size;

    // ---- CSR build ----
    hipMemsetAsync(deg, 0, (size_t)N * 4, stream);
    hist_kernel<<<(E + 255) / 256, 256, 0, stream>>>(e_rows, deg, E);
    scan_kernel<<<1, 1024, 0, stream>>>(deg, rowptr, cursor, N);
    scatter_kernel<<<(E + 255) / 256, 256, 0, stream>>>(e_rows, e_cols, e_vals, cursor, scol, sval, E);

    // ---- layer 1 ----
    gemm_nk128<256><<<(N + 31) / 32, 256, 0, stream>>>(x, w1, bufA, N);
    spmm_kernel<false><<<(N + 3) / 4, 256, 0, stream>>>(rowptr, scol, sval, bufA, b1, nullptr, nullptr, bufB, N);

    // ---- layer 2 + output ----
    gemm_nk128<128><<<(N + 31) / 32, 256, 0, stream>>>(bufB, w2, bufA, N);
    spmm_kernel<true><<<(N + 3) / 4, 256, 0, stream>>>(rowptr, scol, sval, bufA, b2, wo, bo, z, N);
}

// Round 2
// 1035.896 us; speedup vs baseline: 1.3781x; 1.3781x over previous
//
#include <hip/hip_runtime.h>
#include <hip/hip_bf16.h>

// SimpleSAGE on MI355X.
// Pipeline (uses linearity: spmm(x) @ W == spmm(x @ W)):
//   xw  = x @ w1                      [N,128]  (gemm, K=256)
//   h1  = relu(spmm(xw) + b1)         [N,128]  (csr spmm, fused epilogue)
//   h1w = h1 @ w2                     [N,128]  (gemm, K=128)
//   z   = relu(spmm(h1w) + b2)@wo+bo  [N]      (csr spmm, fused epilogue+reduce)
// CSR built on-device every call. Edge payload packed as int2{col, val_bits}.

#define HID 128

// ---------------- CSR build ----------------
__global__ __launch_bounds__(256) void hist_kernel(const int* __restrict__ rows,
                                                   int* __restrict__ deg, int E) {
    int i = blockIdx.x * blockDim.x + threadIdx.x;
    int e4 = i * 4;
    if (e4 + 4 <= E) {
        const int4 r4 = *reinterpret_cast<const int4*>(&rows[e4]);
        atomicAdd(&deg[r4.x], 1);
        atomicAdd(&deg[r4.y], 1);
        atomicAdd(&deg[r4.z], 1);
        atomicAdd(&deg[r4.w], 1);
    } else {
        for (int e = e4; e < E; ++e) atomicAdd(&deg[rows[e]], 1);
    }
}

// coalesced 3-phase scan: per-block sums -> scan sums -> emit offsets
__global__ __launch_bounds__(256) void block_sum_kernel(const int* __restrict__ deg,
                                                        int* __restrict__ bsums, int n) {
    __shared__ int s[256];
    int t = threadIdx.x;
    int i = blockIdx.x * 256 + t;
    s[t] = (i < n) ? deg[i] : 0;
    __syncthreads();
    for (int off = 128; off > 0; off >>= 1) {
        if (t < off) s[t] += s[t + off];
        __syncthreads();
    }
    if (t == 0) bsums[blockIdx.x] = s[0];
}

__global__ __launch_bounds__(512) void scan_sums_kernel(int* __restrict__ bsums, int nb,
                                                        int* __restrict__ rowptr, int n) {
    __shared__ int s[512];
    int t = threadIdx.x;
    int v = (t < nb) ? bsums[t] : 0;
    s[t] = v;
    __syncthreads();
    for (int off = 1; off < 512; off <<= 1) {
        int u = (t >= off) ? s[t - off] : 0;
        __syncthreads();
        s[t] += u;
        __syncthreads();
    }
    if (t < nb) bsums[t] = s[t] - v;      // exclusive block offset
    if (t == 0) rowptr[n] = s[nb - 1];    // total edge count
}

__global__ __launch_bounds__(256) void emit_kernel(const int* __restrict__ deg,
                                                   const int* __restrict__ boffs,
                                                   int* __restrict__ rowptr,
                                                   int* __restrict__ cursor, int n) {
    __shared__ int s[256];
    int t = threadIdx.x;
    int i = blockIdx.x * 256 + t;
    int v = (i < n) ? deg[i] : 0;
    s[t] = v;
    __syncthreads();
    for (int off = 1; off < 256; off <<= 1) {
        int u = (t >= off) ? s[t - off] : 0;
        __syncthreads();
        s[t] += u;
        __syncthreads();
    }
    if (i < n) {
        int excl = boffs[blockIdx.x] + s[t] - v;
        rowptr[i] = excl;
        cursor[i] = excl;
    }
}

__global__ __launch_bounds__(256) void scatter_kernel(const int* __restrict__ rows,
                                                      const int* __restrict__ cols,
                                                      const float* __restrict__ vals,
                                                      int* __restrict__ cursor,
                                                      int2* __restrict__ epair, int E) {
    int i = blockIdx.x * blockDim.x + threadIdx.x;
    int e4 = i * 4;
    if (e4 + 4 <= E) {
        const int4 r4 = *reinterpret_cast<const int4*>(&rows[e4]);
        const int4 c4 = *reinterpret_cast<const int4*>(&cols[e4]);
        const float4 v4 = *reinterpret_cast<const float4*>(&vals[e4]);
        int p;
        p = atomicAdd(&cursor[r4.x], 1); epair[p] = make_int2(c4.x, __float_as_int(v4.x));
        p = atomicAdd(&cursor[r4.y], 1); epair[p] = make_int2(c4.y, __float_as_int(v4.y));
        p = atomicAdd(&cursor[r4.z], 1); epair[p] = make_int2(c4.z, __float_as_int(v4.z));
        p = atomicAdd(&cursor[r4.w], 1); epair[p] = make_int2(c4.w, __float_as_int(v4.w));
    } else {
        for (int e = e4; e < E; ++e) {
            int p = atomicAdd(&cursor[rows[e]], 1);
            epair[p] = make_int2(cols[e], __float_as_int(vals[e]));
        }
    }
}

// ---------------- dense GEMM: C[N,128] = A[N,K] @ W[K,128] ----------------
template <int K>
__global__ __launch_bounds__(256) void gemm_nk128(const float* __restrict__ A,
                                                  const float* __restrict__ W,
                                                  float* __restrict__ C, int nrows) {
    __shared__ float a_s[32][32];
    __shared__ float w_s[32][128];
    const int t = threadIdx.x;
    const int tx = t & 31;   // col group (4 cols each)
    const int ty = t >> 5;   // row group (4 rows each)
    const int row0 = blockIdx.x * 32;
    const int col = tx * 4;
    float acc[4][4] = {};

    for (int k0 = 0; k0 < K; k0 += 32) {
        {
            int r = t >> 3;
            int kk = (t & 7) * 4;
            int gr = row0 + r;
            if (gr >= nrows) gr = nrows - 1;
            const float4 av = *reinterpret_cast<const float4*>(&A[(size_t)gr * K + k0 + kk]);
            *reinterpret_cast<float4*>(&a_s[r][kk]) = av;
        }
        #pragma unroll
        for (int i = 0; i < 4; ++i) {
            int idx4 = t + i * 256;
            int kk = idx4 >> 5;
            int cc = (idx4 & 31) * 4;
            const float4 wv = *reinterpret_cast<const float4*>(&W[(size_t)(k0 + kk) * 128 + cc]);
            *reinterpret_cast<float4*>(&w_s[kk][cc]) = wv;
        }
        __syncthreads();
        #pragma unroll
        for (int kk = 0; kk < 32; kk += 4) {
            float4 a4[4];
            #pragma unroll
            for (int i = 0; i < 4; ++i)
                a4[i] = *reinterpret_cast<const float4*>(&a_s[ty * 4 + i][kk]);
            #pragma unroll
            for (int q = 0; q < 4; ++q) {
                float4 w4 = *reinterpret_cast<const float4*>(&w_s[kk + q][col]);
                #pragma unroll
                for (int i = 0; i < 4; ++i) {
                    float a = (&a4[i].x)[q];
                    acc[i][0] += a * w4.x;
                    acc[i][1] += a * w4.y;
                    acc[i][2] += a * w4.z;
                    acc[i][3] += a * w4.w;
                }
            }
        }
        __syncthreads();
    }
    #pragma unroll
    for (int i = 0; i < 4; ++i) {
        int r = row0 + ty * 4 + i;
        if (r < nrows) {
            float4 v = make_float4(acc[i][0], acc[i][1], acc[i][2], acc[i][3]);
            *reinterpret_cast<float4*>(&C[(size_t)r * HID + col]) = v;
        }
    }
}

// ---------------- CSR SpMM, one wave per row, lane owns 2 features ----------------
// 8-edge manual unroll for memory-level parallelism (8 outstanding gathers/wave).
template <bool FINAL>
__global__ __launch_bounds__(256) void spmm_kernel(const int* __restrict__ row_ptr,
                                                   const int2* __restrict__ epair,
                                                   const float* __restrict__ X,
                                                   const float* __restrict__ bias,
                                                   const float* __restrict__ wo,
                                                   const float* __restrict__ bo,
                                                   float* __restrict__ out, int nrows) {
    const int wave = threadIdx.x >> 6;
    const int lane = threadIdx.x & 63;
    const int row = blockIdx.x * 4 + wave;
    if (row >= nrows) return;
    const int e0 = row_ptr[row];
    const int e1 = row_ptr[row + 1];
    float ax = 0.f, ay = 0.f;
    int e = e0;
    for (; e + 8 <= e1; e += 8) {
        int2 ev[8];
        #pragma unroll
        for (int i = 0; i < 8; ++i) ev[i] = epair[e + i];
        float2 xv[8];
        #pragma unroll
        for (int i = 0; i < 8; ++i)
            xv[i] = *reinterpret_cast<const float2*>(&X[(size_t)ev[i].x * HID + lane * 2]);
        #pragma unroll
        for (int i = 0; i < 8; ++i) {
            const float v = __int_as_float(ev[i].y);
            ax += v * xv[i].x;
            ay += v * xv[i].y;
        }
    }
    for (; e < e1; ++e) {
        const int2 evt = epair[e];
        const float2 xv = *reinterpret_cast<const float2*>(&X[(size_t)evt.x * HID + lane * 2]);
        const float v = __int_as_float(evt.y);
        ax += v * xv.x;
        ay += v * xv.y;
    }
    const float hx = fmaxf(ax + bias[lane * 2], 0.f);
    const float hy = fmaxf(ay + bias[lane * 2 + 1], 0.f);
    if (!FINAL) {
        *reinterpret_cast<float2*>(&out[(size_t)row * HID + lane * 2]) = make_float2(hx, hy);
    } else {
        float p = hx * wo[lane * 2] + hy * wo[lane * 2 + 1];
        #pragma unroll
        for (int off = 32; off > 0; off >>= 1) p += __shfl_down(p, off, 64);
        if (lane == 0) out[row] = p + bo[0];
    }
}

extern "C" void kernel_launch(void* const* d_in, const int* in_sizes, int n_in,
                              void* d_out, int out_size, void* d_ws, size_t ws_size,
                              hipStream_t stream) {
    const float* x        = (const float*)d_in[0];
    const int*   e_rows   = (const int*)d_in[1];
    const int*   e_cols   = (const int*)d_in[2];
    const float* e_vals   = (const float*)d_in[3];
    const float* w1       = (const float*)d_in[4];
    const float* b1       = (const float*)d_in[5];
    const float* w2       = (const float*)d_in[6];
    const float* b2       = (const float*)d_in[7];
    const float* wo       = (const float*)d_in[8];
    const float* bo       = (const float*)d_in[9];
    float* z = (float*)d_out;

    const int IN_DIM = 256;
    const int N = in_sizes[0] / IN_DIM;
    const int E = in_sizes[1];
    const int NB = (N + 255) / 256;   // scan blocks (must be <= 512)

    // workspace carve-up
    size_t off = 0;
    auto alloc = [&](size_t bytes) {
        void* p = (char*)d_ws + off;
        off += (bytes + 255) & ~(size_t)255;
        return p;
    };
    float* bufA   = (float*)alloc((size_t)N * HID * 4);  // xw, later h1w
    float* bufB   = (float*)alloc((size_t)N * HID * 4);  // h1
    int*   deg    = (int*)alloc((size_t)N * 4);
    int*   rowptr = (int*)alloc((size_t)(N + 1) * 4);
    int*   cursor = (int*)alloc((size_t)N * 4);
    int*   bsums  = (int*)alloc((size_t)NB * 4);
    int2*  epair  = (int2*)alloc((size_t)E * 8);
    (void)ws_size;

    // ---- CSR build ----
    hipMemsetAsync(deg, 0, (size_t)N * 4, stream);
    const int E4 = (E + 3) / 4;
    hist_kernel<<<(E4 + 255) / 256, 256, 0, stream>>>(e_rows, deg, E);
    block_sum_kernel<<<NB, 256, 0, stream>>>(deg, bsums, N);
    scan_sums_kernel<<<1, 512, 0, stream>>>(bsums, NB, rowptr, N);
    emit_kernel<<<NB, 256, 0, stream>>>(deg, bsums, rowptr, cursor, N);
    scatter_kernel<<<(E4 + 255) / 256, 256, 0, stream>>>(e_rows, e_cols, e_vals, cursor, epair, E);

    // ---- layer 1 ----
    gemm_nk128<256><<<(N + 31) / 32, 256, 0, stream>>>(x, w1, bufA, N);
    spmm_kernel<false><<<(N + 3) / 4, 256, 0, stream>>>(rowptr, epair, bufA, b1, nullptr, nullptr, bufB, N);

    // ---- layer 2 + output ----
    gemm_nk128<128><<<(N + 31) / 32, 256, 0, stream>>>(bufB, w2, bufA, N);
    spmm_kernel<true><<<(N + 3) / 4, 256, 0, stream>>>(rowptr, epair, bufA, b2, wo, bo, z, N);
}

// Round 3
// 862.779 us; speedup vs baseline: 1.6546x; 1.2007x over previous
//
#include <hip/hip_runtime.h>
#include <hip/hip_bf16.h>

// SimpleSAGE on MI355X.
// Pipeline (uses linearity: spmm(x) @ W == spmm(x @ W)):
//   xw  = x @ w1                      [N,128]  (gemm, K=256)
//   h1  = relu(spmm(xw) + b1)         [N,128]  (csr spmm, fused epilogue)
//   h1w = h1 @ w2                     [N,128]  (gemm, K=128)
//   z   = relu(spmm(h1w) + b2)@wo+bo  [N]      (csr spmm, fused epilogue+reduce)
// CSR built per-call via 2-phase radix partition (bucket = row>>9):
//   bhist -> bscan -> partition (chunk-local LDS cursors, packed {col|rowrel<<17,val})
//   -> finalize (per-bucket LDS row-scan, writes rowptr + final epair in L2-warm window)
// Requires N <= 131072 (col packs in 17 bits) and N <= 262144 (512-entry LDS tables).

#define HID 128
#define CHUNK_E 16384

// ---------------- CSR build: radix partition ----------------
__global__ __launch_bounds__(256) void bhist_kernel(const int* __restrict__ rows,
                                                    int* __restrict__ histT,
                                                    int E, int nbucket, int nchunk) {
    __shared__ int h[512];
    const int t = threadIdx.x;
    const int c = blockIdx.x;
    for (int b = t; b < nbucket; b += 256) h[b] = 0;
    __syncthreads();
    const int estart = c * CHUNK_E;
    const int eend = min(estart + CHUNK_E, E);
    for (int e4 = estart + t * 4; e4 < eend; e4 += 1024) {
        if (e4 + 4 <= eend) {
            const int4 r4 = *reinterpret_cast<const int4*>(&rows[e4]);
            atomicAdd(&h[r4.x >> 9], 1);
            atomicAdd(&h[r4.y >> 9], 1);
            atomicAdd(&h[r4.z >> 9], 1);
            atomicAdd(&h[r4.w >> 9], 1);
        } else {
            for (int e = e4; e < eend; ++e) atomicAdd(&h[rows[e] >> 9], 1);
        }
    }
    __syncthreads();
    for (int b = t; b < nbucket; b += 256) histT[b * nchunk + c] = h[b];
}

__global__ __launch_bounds__(1024) void bscan_kernel(int* __restrict__ histT, int ntot,
                                                     int* __restrict__ rowptr, int n, int E) {
    __shared__ int s[1024];
    const int t = threadIdx.x;
    const int seq = (ntot + 1023) >> 10;
    const int i0 = t * seq;
    const int i1 = min(i0 + seq, ntot);
    int sum = 0;
    for (int i = i0; i < i1; ++i) sum += histT[i];
    s[t] = sum;
    __syncthreads();
    for (int off = 1; off < 1024; off <<= 1) {
        int u = (t >= off) ? s[t - off] : 0;
        __syncthreads();
        s[t] += u;
        __syncthreads();
    }
    int run = s[t] - sum;  // exclusive prefix of this thread's segment
    for (int i = i0; i < i1; ++i) {
        int v = histT[i];
        histT[i] = run;
        run += v;
    }
    if (t == 0) rowptr[n] = E;
}

__global__ __launch_bounds__(256) void partition_kernel(const int* __restrict__ rows,
                                                        const int* __restrict__ cols,
                                                        const float* __restrict__ vals,
                                                        const int* __restrict__ baseT,
                                                        int2* __restrict__ bcv,
                                                        int E, int nbucket, int nchunk) {
    __shared__ int cur[512];
    const int t = threadIdx.x;
    const int c = blockIdx.x;
    for (int b = t; b < nbucket; b += 256) cur[b] = baseT[b * nchunk + c];
    __syncthreads();
    const int estart = c * CHUNK_E;
    const int eend = min(estart + CHUNK_E, E);
    for (int e4 = estart + t * 4; e4 < eend; e4 += 1024) {
        if (e4 + 4 <= eend) {
            const int4 r4 = *reinterpret_cast<const int4*>(&rows[e4]);
            const int4 c4 = *reinterpret_cast<const int4*>(&cols[e4]);
            const float4 v4 = *reinterpret_cast<const float4*>(&vals[e4]);
            int p;
            p = atomicAdd(&cur[r4.x >> 9], 1);
            bcv[p] = make_int2(c4.x | ((r4.x & 511) << 17), __float_as_int(v4.x));
            p = atomicAdd(&cur[r4.y >> 9], 1);
            bcv[p] = make_int2(c4.y | ((r4.y & 511) << 17), __float_as_int(v4.y));
            p = atomicAdd(&cur[r4.z >> 9], 1);
            bcv[p] = make_int2(c4.z | ((r4.z & 511) << 17), __float_as_int(v4.z));
            p = atomicAdd(&cur[r4.w >> 9], 1);
            bcv[p] = make_int2(c4.w | ((r4.w & 511) << 17), __float_as_int(v4.w));
        } else {
            for (int e = e4; e < eend; ++e) {
                int r = rows[e];
                int p = atomicAdd(&cur[r >> 9], 1);
                bcv[p] = make_int2(cols[e] | ((r & 511) << 17), __float_as_int(vals[e]));
            }
        }
    }
}

__global__ __launch_bounds__(256) void finalize_kernel(const int2* __restrict__ bcv,
                                                       const int* __restrict__ baseT,
                                                       int* __restrict__ rowptr,
                                                       int2* __restrict__ epair,
                                                       int N, int E, int nchunk, int nbucket) {
    __shared__ int cnt[512];
    __shared__ int part[256];
    const int t = threadIdx.x;
    const int b = blockIdx.x;
    const int rowbase = b << 9;
    const int nrows_b = min(512, N - rowbase);
    const int bstart = baseT[b * nchunk];
    const int bend = (b + 1 < nbucket) ? baseT[(b + 1) * nchunk] : E;
    cnt[t] = 0;
    cnt[t + 256] = 0;
    __syncthreads();
    for (int e = bstart + t; e < bend; e += 256) {
        const int w0 = reinterpret_cast<const int*>(bcv)[2 * e];
        atomicAdd(&cnt[w0 >> 17], 1);
    }
    __syncthreads();
    // exclusive scan of cnt[0..511] with 256 threads (2 elems each)
    const int a0 = cnt[2 * t];
    const int a1 = cnt[2 * t + 1];
    part[t] = a0 + a1;
    __syncthreads();
    for (int off = 1; off < 256; off <<= 1) {
        int u = (t >= off) ? part[t - off] : 0;
        __syncthreads();
        part[t] += u;
        __syncthreads();
    }
    const int excl = part[t] - (a0 + a1);
    cnt[2 * t] = bstart + excl;
    cnt[2 * t + 1] = bstart + excl + a0;
    if (2 * t < nrows_b) rowptr[rowbase + 2 * t] = bstart + excl;
    if (2 * t + 1 < nrows_b) rowptr[rowbase + 2 * t + 1] = bstart + excl + a0;
    __syncthreads();
    for (int e = bstart + t; e < bend; e += 256) {
        const int2 w = bcv[e];
        const int p = atomicAdd(&cnt[w.x >> 17], 1);
        epair[p] = make_int2(w.x & 0x1FFFF, w.y);
    }
}

// ---------------- dense GEMM: C[N,128] = A[N,K] @ W[K,128] ----------------
template <int K>
__global__ __launch_bounds__(256) void gemm_nk128(const float* __restrict__ A,
                                                  const float* __restrict__ W,
                                                  float* __restrict__ C, int nrows) {
    __shared__ float a_s[32][32];
    __shared__ float w_s[32][128];
    const int t = threadIdx.x;
    const int tx = t & 31;   // col group (4 cols each)
    const int ty = t >> 5;   // row group (4 rows each)
    const int row0 = blockIdx.x * 32;
    const int col = tx * 4;
    float acc[4][4] = {};

    for (int k0 = 0; k0 < K; k0 += 32) {
        {
            int r = t >> 3;
            int kk = (t & 7) * 4;
            int gr = row0 + r;
            if (gr >= nrows) gr = nrows - 1;
            const float4 av = *reinterpret_cast<const float4*>(&A[(size_t)gr * K + k0 + kk]);
            *reinterpret_cast<float4*>(&a_s[r][kk]) = av;
        }
        #pragma unroll
        for (int i = 0; i < 4; ++i) {
            int idx4 = t + i * 256;
            int kk = idx4 >> 5;
            int cc = (idx4 & 31) * 4;
            const float4 wv = *reinterpret_cast<const float4*>(&W[(size_t)(k0 + kk) * 128 + cc]);
            *reinterpret_cast<float4*>(&w_s[kk][cc]) = wv;
        }
        __syncthreads();
        #pragma unroll
        for (int kk = 0; kk < 32; kk += 4) {
            float4 a4[4];
            #pragma unroll
            for (int i = 0; i < 4; ++i)
                a4[i] = *reinterpret_cast<const float4*>(&a_s[ty * 4 + i][kk]);
            #pragma unroll
            for (int q = 0; q < 4; ++q) {
                float4 w4 = *reinterpret_cast<const float4*>(&w_s[kk + q][col]);
                #pragma unroll
                for (int i = 0; i < 4; ++i) {
                    float a = (&a4[i].x)[q];
                    acc[i][0] += a * w4.x;
                    acc[i][1] += a * w4.y;
                    acc[i][2] += a * w4.z;
                    acc[i][3] += a * w4.w;
                }
            }
        }
        __syncthreads();
    }
    #pragma unroll
    for (int i = 0; i < 4; ++i) {
        int r = row0 + ty * 4 + i;
        if (r < nrows) {
            float4 v = make_float4(acc[i][0], acc[i][1], acc[i][2], acc[i][3]);
            *reinterpret_cast<float4*>(&C[(size_t)r * HID + col]) = v;
        }
    }
}

// ---------------- CSR SpMM, one wave per row, lane owns 2 features ----------------
template <bool FINAL>
__global__ __launch_bounds__(256) void spmm_kernel(const int* __restrict__ row_ptr,
                                                   const int2* __restrict__ epair,
                                                   const float* __restrict__ X,
                                                   const float* __restrict__ bias,
                                                   const float* __restrict__ wo,
                                                   const float* __restrict__ bo,
                                                   float* __restrict__ out, int nrows) {
    const int wave = threadIdx.x >> 6;
    const int lane = threadIdx.x & 63;
    const int row = blockIdx.x * 4 + wave;
    if (row >= nrows) return;
    const int e0 = row_ptr[row];
    const int e1 = row_ptr[row + 1];
    float ax = 0.f, ay = 0.f;
    int e = e0;
    for (; e + 8 <= e1; e += 8) {
        int2 ev[8];
        #pragma unroll
        for (int i = 0; i < 8; ++i) ev[i] = epair[e + i];
        float2 xv[8];
        #pragma unroll
        for (int i = 0; i < 8; ++i)
            xv[i] = *reinterpret_cast<const float2*>(&X[(size_t)ev[i].x * HID + lane * 2]);
        #pragma unroll
        for (int i = 0; i < 8; ++i) {
            const float v = __int_as_float(ev[i].y);
            ax += v * xv[i].x;
            ay += v * xv[i].y;
        }
    }
    for (; e < e1; ++e) {
        const int2 evt = epair[e];
        const float2 xv = *reinterpret_cast<const float2*>(&X[(size_t)evt.x * HID + lane * 2]);
        const float v = __int_as_float(evt.y);
        ax += v * xv.x;
        ay += v * xv.y;
    }
    const float hx = fmaxf(ax + bias[lane * 2], 0.f);
    const float hy = fmaxf(ay + bias[lane * 2 + 1], 0.f);
    if (!FINAL) {
        *reinterpret_cast<float2*>(&out[(size_t)row * HID + lane * 2]) = make_float2(hx, hy);
    } else {
        float p = hx * wo[lane * 2] + hy * wo[lane * 2 + 1];
        #pragma unroll
        for (int off = 32; off > 0; off >>= 1) p += __shfl_down(p, off, 64);
        if (lane == 0) out[row] = p + bo[0];
    }
}

extern "C" void kernel_launch(void* const* d_in, const int* in_sizes, int n_in,
                              void* d_out, int out_size, void* d_ws, size_t ws_size,
                              hipStream_t stream) {
    const float* x        = (const float*)d_in[0];
    const int*   e_rows   = (const int*)d_in[1];
    const int*   e_cols   = (const int*)d_in[2];
    const float* e_vals   = (const float*)d_in[3];
    const float* w1       = (const float*)d_in[4];
    const float* b1       = (const float*)d_in[5];
    const float* w2       = (const float*)d_in[6];
    const float* b2       = (const float*)d_in[7];
    const float* wo       = (const float*)d_in[8];
    const float* bo       = (const float*)d_in[9];
    float* z = (float*)d_out;

    const int IN_DIM = 256;
    const int N = in_sizes[0] / IN_DIM;
    const int E = in_sizes[1];
    const int NCHUNK = (E + CHUNK_E - 1) / CHUNK_E;
    const int NBUCKET = (N + 511) >> 9;

    // workspace carve-up
    size_t off = 0;
    auto alloc = [&](size_t bytes) {
        void* p = (char*)d_ws + off;
        off += (bytes + 255) & ~(size_t)255;
        return p;
    };
    float* bufA   = (float*)alloc((size_t)N * HID * 4);           // xw, later h1w
    float* bufB   = (float*)alloc((size_t)N * HID * 4);           // h1 (aliased by bcv during build)
    int*   rowptr = (int*)alloc((size_t)(N + 1) * 4);
    int*   histT  = (int*)alloc((size_t)NBUCKET * NCHUNK * 4);    // -> baseT after scan
    int2*  epair  = (int2*)alloc((size_t)E * 8);
    int2*  bcv    = (int2*)bufB;  // staging partition, consumed before spmm1 writes bufB
    (void)ws_size;

    // ---- CSR build (radix partition) ----
    bhist_kernel<<<NCHUNK, 256, 0, stream>>>(e_rows, histT, E, NBUCKET, NCHUNK);
    bscan_kernel<<<1, 1024, 0, stream>>>(histT, NBUCKET * NCHUNK, rowptr, N, E);
    partition_kernel<<<NCHUNK, 256, 0, stream>>>(e_rows, e_cols, e_vals, histT, bcv, E, NBUCKET, NCHUNK);
    finalize_kernel<<<NBUCKET, 256, 0, stream>>>(bcv, histT, rowptr, epair, N, E, NCHUNK, NBUCKET);

    // ---- layer 1 ----
    gemm_nk128<256><<<(N + 31) / 32, 256, 0, stream>>>(x, w1, bufA, N);
    spmm_kernel<false><<<(N + 3) / 4, 256, 0, stream>>>(rowptr, epair, bufA, b1, nullptr, nullptr, bufB, N);

    // ---- layer 2 + output ----
    gemm_nk128<128><<<(N + 31) / 32, 256, 0, stream>>>(bufB, w2, bufA, N);
    spmm_kernel<true><<<(N + 3) / 4, 256, 0, stream>>>(rowptr, epair, bufA, b2, wo, bo, z, N);
}

// Round 4
// 632.697 us; speedup vs baseline: 2.2563x; 1.3637x over previous
//
#include <hip/hip_runtime.h>
#include <hip/hip_bf16.h>

// SimpleSAGE on MI355X — bf16 feature pipeline + MFMA GEMMs.
//   xw  = x @ w1                      [N,128] bf16  (mfma gemm, K=256, A fp32->bf16)
//   h1  = relu(spmm(xw) + b1)         [N,128] bf16  (csr spmm, bf16 gather, fp32 acc)
//   h1w = h1 @ w2                     [N,128] bf16  (mfma gemm, K=128, A bf16)
//   z   = relu(spmm(h1w) + b2)@wo+bo  [N]   fp32
// CSR built per-call via 2-phase radix partition (bucket = row>>9).

#define HID 128
#define CHUNK_E 16384

typedef __attribute__((ext_vector_type(8))) short bf16x8;
typedef __attribute__((ext_vector_type(4))) float f32x4;

__device__ __forceinline__ ushort f2bf(float f) {
    union { float f; unsigned u; } v; v.f = f;
    unsigned r = v.u + 0x7fffu + ((v.u >> 16) & 1u);  // RNE
    return (ushort)(r >> 16);
}
__device__ __forceinline__ float bf2f(ushort u) {
    return __uint_as_float(((unsigned)u) << 16);
}

// ---------------- CSR build: radix partition ----------------
__global__ __launch_bounds__(256) void bhist_kernel(const int* __restrict__ rows,
                                                    int* __restrict__ histT,
                                                    int E, int nbucket, int nchunk) {
    __shared__ int h[512];
    const int t = threadIdx.x;
    const int c = blockIdx.x;
    for (int b = t; b < nbucket; b += 256) h[b] = 0;
    __syncthreads();
    const int estart = c * CHUNK_E;
    const int eend = min(estart + CHUNK_E, E);
    for (int e4 = estart + t * 4; e4 < eend; e4 += 1024) {
        if (e4 + 4 <= eend) {
            const int4 r4 = *reinterpret_cast<const int4*>(&rows[e4]);
            atomicAdd(&h[r4.x >> 9], 1);
            atomicAdd(&h[r4.y >> 9], 1);
            atomicAdd(&h[r4.z >> 9], 1);
            atomicAdd(&h[r4.w >> 9], 1);
        } else {
            for (int e = e4; e < eend; ++e) atomicAdd(&h[rows[e] >> 9], 1);
        }
    }
    __syncthreads();
    for (int b = t; b < nbucket; b += 256) histT[b * nchunk + c] = h[b];
}

__global__ __launch_bounds__(1024) void bscan_kernel(int* __restrict__ histT, int ntot,
                                                     int* __restrict__ rowptr, int n, int E) {
    __shared__ int s[1024];
    const int t = threadIdx.x;
    const int seq = (ntot + 1023) >> 10;
    const int i0 = t * seq;
    const int i1 = min(i0 + seq, ntot);
    int sum = 0;
    for (int i = i0; i < i1; ++i) sum += histT[i];
    s[t] = sum;
    __syncthreads();
    for (int off = 1; off < 1024; off <<= 1) {
        int u = (t >= off) ? s[t - off] : 0;
        __syncthreads();
        s[t] += u;
        __syncthreads();
    }
    int run = s[t] - sum;
    for (int i = i0; i < i1; ++i) {
        int v = histT[i];
        histT[i] = run;
        run += v;
    }
    if (t == 0) rowptr[n] = E;
}

__global__ __launch_bounds__(256) void partition_kernel(const int* __restrict__ rows,
                                                        const int* __restrict__ cols,
                                                        const float* __restrict__ vals,
                                                        const int* __restrict__ baseT,
                                                        int2* __restrict__ bcv,
                                                        int E, int nbucket, int nchunk) {
    __shared__ int cur[512];
    const int t = threadIdx.x;
    const int c = blockIdx.x;
    for (int b = t; b < nbucket; b += 256) cur[b] = baseT[b * nchunk + c];
    __syncthreads();
    const int estart = c * CHUNK_E;
    const int eend = min(estart + CHUNK_E, E);
    for (int e4 = estart + t * 4; e4 < eend; e4 += 1024) {
        if (e4 + 4 <= eend) {
            const int4 r4 = *reinterpret_cast<const int4*>(&rows[e4]);
            const int4 c4 = *reinterpret_cast<const int4*>(&cols[e4]);
            const float4 v4 = *reinterpret_cast<const float4*>(&vals[e4]);
            int p;
            p = atomicAdd(&cur[r4.x >> 9], 1);
            bcv[p] = make_int2(c4.x | ((r4.x & 511) << 17), __float_as_int(v4.x));
            p = atomicAdd(&cur[r4.y >> 9], 1);
            bcv[p] = make_int2(c4.y | ((r4.y & 511) << 17), __float_as_int(v4.y));
            p = atomicAdd(&cur[r4.z >> 9], 1);
            bcv[p] = make_int2(c4.z | ((r4.z & 511) << 17), __float_as_int(v4.z));
            p = atomicAdd(&cur[r4.w >> 9], 1);
            bcv[p] = make_int2(c4.w | ((r4.w & 511) << 17), __float_as_int(v4.w));
        } else {
            for (int e = e4; e < eend; ++e) {
                int r = rows[e];
                int p = atomicAdd(&cur[r >> 9], 1);
                bcv[p] = make_int2(cols[e] | ((r & 511) << 17), __float_as_int(vals[e]));
            }
        }
    }
}

__global__ __launch_bounds__(256) void finalize_kernel(const int2* __restrict__ bcv,
                                                       const int* __restrict__ baseT,
                                                       int* __restrict__ rowptr,
                                                       int2* __restrict__ epair,
                                                       int N, int E, int nchunk, int nbucket) {
    __shared__ int cnt[512];
    __shared__ int part[256];
    const int t = threadIdx.x;
    const int b = blockIdx.x;
    const int rowbase = b << 9;
    const int nrows_b = min(512, N - rowbase);
    const int bstart = baseT[b * nchunk];
    const int bend = (b + 1 < nbucket) ? baseT[(b + 1) * nchunk] : E;
    cnt[t] = 0;
    cnt[t + 256] = 0;
    __syncthreads();
    for (int e = bstart + t; e < bend; e += 256) {
        const int w0 = reinterpret_cast<const int*>(bcv)[2 * e];
        atomicAdd(&cnt[w0 >> 17], 1);
    }
    __syncthreads();
    const int a0 = cnt[2 * t];
    const int a1 = cnt[2 * t + 1];
    part[t] = a0 + a1;
    __syncthreads();
    for (int off = 1; off < 256; off <<= 1) {
        int u = (t >= off) ? part[t - off] : 0;
        __syncthreads();
        part[t] += u;
        __syncthreads();
    }
    const int excl = part[t] - (a0 + a1);
    cnt[2 * t] = bstart + excl;
    cnt[2 * t + 1] = bstart + excl + a0;
    if (2 * t < nrows_b) rowptr[rowbase + 2 * t] = bstart + excl;
    if (2 * t + 1 < nrows_b) rowptr[rowbase + 2 * t + 1] = bstart + excl + a0;
    __syncthreads();
    for (int e = bstart + t; e < bend; e += 256) {
        const int2 w = bcv[e];
        const int p = atomicAdd(&cnt[w.x >> 17], 1);
        epair[p] = make_int2(w.x & 0x1FFFF, w.y);
    }
}

// ---------------- MFMA GEMM: C[N,128](bf16) = A[N,K] @ W[K,128] ----------------
// Block 256 thr = 4 waves; block tile 128 rows; wave tile 32 rows x 128 cols.
// W^T staged in LDS bf16, XOR-swizzled (byte ^= (col&7)<<4) for conflict-free b128.
// A/B fragments both packed with k-map k = 8*(lane>>4) + slot; correctness holds for
// any true HW k-layout since A and B share the same (group,slot)->k structure.
template <int K, bool ABF16>
__global__ __launch_bounds__(256) void mfma_gemm(const void* __restrict__ Aptr,
                                                 const float* __restrict__ W,
                                                 ushort* __restrict__ C, int nrows) {
    __shared__ __align__(16) ushort wt[128 * K];
    const int t = threadIdx.x;
    // stage W^T as bf16 (reads coalesced, scattered u16 LDS writes)
    for (int idx = t; idx < K * 32; idx += 256) {
        const int c4 = (idx & 31) << 2;
        const int k = idx >> 5;
        const float4 w4 = *reinterpret_cast<const float4*>(&W[k * 128 + c4]);
        const float wf[4] = {w4.x, w4.y, w4.z, w4.w};
        #pragma unroll
        for (int j = 0; j < 4; ++j) {
            const int c = c4 + j;
            const unsigned byteoff = (unsigned)(((c * K + k) * 2) ^ ((c & 7) << 4));
            *reinterpret_cast<ushort*>(reinterpret_cast<char*>(wt) + byteoff) = f2bf(wf[j]);
        }
    }
    __syncthreads();

    const int lane = t & 63;
    const int wv = t >> 6;
    const int r = lane & 15;
    const int g = lane >> 4;
    const int row_base = blockIdx.x * 128 + wv * 32;
    const unsigned xorv = (unsigned)((r & 7) << 4);
    f32x4 acc[2][8] = {};

    for (int s = 0; s < K / 32; ++s) {
        const int kb = s * 32 + g * 8;
        bf16x8 a[2];
        #pragma unroll
        for (int f = 0; f < 2; ++f) {
            int row = row_base + f * 16 + r;
            if (row >= nrows) row = nrows - 1;
            if (ABF16) {
                a[f] = *reinterpret_cast<const bf16x8*>(
                    (const ushort*)Aptr + (size_t)row * K + kb);
            } else {
                const float* Af = (const float*)Aptr + (size_t)row * K + kb;
                const float4 v0 = *reinterpret_cast<const float4*>(Af);
                const float4 v1 = *reinterpret_cast<const float4*>(Af + 4);
                bf16x8 av;
                av[0] = (short)f2bf(v0.x); av[1] = (short)f2bf(v0.y);
                av[2] = (short)f2bf(v0.z); av[3] = (short)f2bf(v0.w);
                av[4] = (short)f2bf(v1.x); av[5] = (short)f2bf(v1.y);
                av[6] = (short)f2bf(v1.z); av[7] = (short)f2bf(v1.w);
                a[f] = av;
            }
        }
        #pragma unroll
        for (int c = 0; c < 8; ++c) {
            const unsigned boff = ((unsigned)(((c * 16 + r) * K + kb) * 2)) ^ xorv;
            const bf16x8 b = *reinterpret_cast<const bf16x8*>(
                reinterpret_cast<char*>(wt) + boff);
            acc[0][c] = __builtin_amdgcn_mfma_f32_16x16x32_bf16(a[0], b, acc[0][c], 0, 0, 0);
            acc[1][c] = __builtin_amdgcn_mfma_f32_16x16x32_bf16(a[1], b, acc[1][c], 0, 0, 0);
        }
    }
    // epilogue: C/D map col=lane&15, row=4*(lane>>4)+j (m89-verified)
    #pragma unroll
    for (int f = 0; f < 2; ++f) {
        #pragma unroll
        for (int j = 0; j < 4; ++j) {
            const int row = row_base + f * 16 + g * 4 + j;
            if (row < nrows) {
                #pragma unroll
                for (int c = 0; c < 8; ++c) {
                    C[(size_t)row * HID + c * 16 + r] = f2bf(acc[f][c][j]);
                }
            }
        }
    }
}

// ---------------- CSR SpMM (bf16 gather), one wave per row, lane owns 2 features ----
template <bool FINAL>
__global__ __launch_bounds__(256) void spmm_kernel(const int* __restrict__ row_ptr,
                                                   const int2* __restrict__ epair,
                                                   const ushort* __restrict__ X,
                                                   const float* __restrict__ bias,
                                                   const float* __restrict__ wo,
                                                   const float* __restrict__ bo,
                                                   void* __restrict__ out, int nrows) {
    const int wave = threadIdx.x >> 6;
    const int lane = threadIdx.x & 63;
    const int row = blockIdx.x * 4 + wave;
    if (row >= nrows) return;
    const int e0 = row_ptr[row];
    const int e1 = row_ptr[row + 1];
    float ax = 0.f, ay = 0.f;
    int e = e0;
    for (; e + 8 <= e1; e += 8) {
        int2 ev[8];
        #pragma unroll
        for (int i = 0; i < 8; ++i) ev[i] = epair[e + i];
        unsigned xv[8];
        #pragma unroll
        for (int i = 0; i < 8; ++i)
            xv[i] = *reinterpret_cast<const unsigned*>(&X[(size_t)ev[i].x * HID + lane * 2]);
        #pragma unroll
        for (int i = 0; i < 8; ++i) {
            const float v = __int_as_float(ev[i].y);
            ax += v * bf2f((ushort)(xv[i] & 0xffffu));
            ay += v * bf2f((ushort)(xv[i] >> 16));
        }
    }
    for (; e < e1; ++e) {
        const int2 evt = epair[e];
        const unsigned xu = *reinterpret_cast<const unsigned*>(&X[(size_t)evt.x * HID + lane * 2]);
        const float v = __int_as_float(evt.y);
        ax += v * bf2f((ushort)(xu & 0xffffu));
        ay += v * bf2f((ushort)(xu >> 16));
    }
    const float hx = fmaxf(ax + bias[lane * 2], 0.f);
    const float hy = fmaxf(ay + bias[lane * 2 + 1], 0.f);
    if (!FINAL) {
        const unsigned packed = (unsigned)f2bf(hx) | ((unsigned)f2bf(hy) << 16);
        reinterpret_cast<unsigned*>(out)[(size_t)row * (HID / 2) + lane] = packed;
    } else {
        float p = hx * wo[lane * 2] + hy * wo[lane * 2 + 1];
        #pragma unroll
        for (int off = 32; off > 0; off >>= 1) p += __shfl_down(p, off, 64);
        if (lane == 0) reinterpret_cast<float*>(out)[row] = p + bo[0];
    }
}

extern "C" void kernel_launch(void* const* d_in, const int* in_sizes, int n_in,
                              void* d_out, int out_size, void* d_ws, size_t ws_size,
                              hipStream_t stream) {
    const float* x        = (const float*)d_in[0];
    const int*   e_rows   = (const int*)d_in[1];
    const int*   e_cols   = (const int*)d_in[2];
    const float* e_vals   = (const float*)d_in[3];
    const float* w1       = (const float*)d_in[4];
    const float* b1       = (const float*)d_in[5];
    const float* w2       = (const float*)d_in[6];
    const float* b2       = (const float*)d_in[7];
    const float* wo       = (const float*)d_in[8];
    const float* bo       = (const float*)d_in[9];
    float* z = (float*)d_out;

    const int IN_DIM = 256;
    const int N = in_sizes[0] / IN_DIM;
    const int E = in_sizes[1];
    const int NCHUNK = (E + CHUNK_E - 1) / CHUNK_E;
    const int NBUCKET = (N + 511) >> 9;

    size_t off = 0;
    auto alloc = [&](size_t bytes) {
        void* p = (char*)d_ws + off;
        off += (bytes + 255) & ~(size_t)255;
        return p;
    };
    ushort* bufA  = (ushort*)alloc((size_t)N * HID * 2);        // xw, later h1w (bf16)
    ushort* bufB  = (ushort*)alloc((size_t)N * HID * 2);        // h1 (bf16)
    int*   rowptr = (int*)alloc((size_t)(N + 1) * 4);
    int*   histT  = (int*)alloc((size_t)NBUCKET * NCHUNK * 4);
    int2*  epair  = (int2*)alloc((size_t)E * 8);
    int2*  bcv    = (int2*)alloc((size_t)E * 8);
    (void)ws_size;

    // ---- CSR build (radix partition) ----
    bhist_kernel<<<NCHUNK, 256, 0, stream>>>(e_rows, histT, E, NBUCKET, NCHUNK);
    bscan_kernel<<<1, 1024, 0, stream>>>(histT, NBUCKET * NCHUNK, rowptr, N, E);
    partition_kernel<<<NCHUNK, 256, 0, stream>>>(e_rows, e_cols, e_vals, histT, bcv, E, NBUCKET, NCHUNK);
    finalize_kernel<<<NBUCKET, 256, 0, stream>>>(bcv, histT, rowptr, epair, N, E, NCHUNK, NBUCKET);

    const int gemm_grid = (N + 127) / 128;
    // ---- layer 1 ----
    mfma_gemm<256, false><<<gemm_grid, 256, 0, stream>>>(x, w1, bufA, N);
    spmm_kernel<false><<<(N + 3) / 4, 256, 0, stream>>>(rowptr, epair, bufA, b1, nullptr, nullptr, bufB, N);

    // ---- layer 2 + output ----
    mfma_gemm<128, true><<<gemm_grid, 256, 0, stream>>>(bufB, w2, bufA, N);
    spmm_kernel<true><<<(N + 3) / 4, 256, 0, stream>>>(rowptr, epair, bufA, b2, wo, bo, z, N);
}